// Round 3
// baseline (238.689 us; speedup 1.0000x reference)
//
#include <hip/hip_runtime.h>

// GCNFast: out[b,s,t,d] = relu( sum_j relu(AA[i%64,j%64]*GCW[i,j]) * X[j,b,d] + GCB[i,d] )
// 2 dispatches:
//   (1) fused prep (unchanged): A=relu(AA*GCW)->bf16 reading only the 64x64 AA
//       tile; h -> XT bf16 [b*128+d][t*64+c] with coalesced writes.
//   (2) gemm: triple-buffered counted-vmcnt pipeline + m201-style PER-PHASE
//       BARRIER DISCIPLINE. Each K-tile = 2 phases: {8 ds_read_b128 + 3 stage
//       loads -> s_barrier -> lgkm wait -> setprio(1) 16 MFMA setprio(0) ->
//       s_barrier}. Waves stagger on the lgkm wait so LDS reads of some waves
//       overlap MFMA of others (fixes the bunched 37.5% = 155/(155+256) regime;
//       staggered ceiling = 155/256 = 60%). vmcnt(6) never drains in main loop.
// Fallback to fused single-kernel path if ws_size < 50.3 MB.

#define NC 64
#define NS 64
#define NT 64
#define DH 128
#define BATCH 16
#define MDIM 4096
#define KDIM 4096
#define TM 128
#define TK 64
#define BM 128
#define BN 256
#define BK 64
#define NTILES (KDIM / BK)

typedef __attribute__((ext_vector_type(8))) short short8;
typedef __attribute__((ext_vector_type(4))) float floatx4;

__device__ __forceinline__ unsigned short f2bf(float f) {
    union { float f; unsigned int i; } v; v.f = f;
    return (unsigned short)((v.i + 0x7fffu + ((v.i >> 16) & 1u)) >> 16);
}
__device__ __forceinline__ void async16(const void* g, void* l) {
    __builtin_amdgcn_global_load_lds(
        (const __attribute__((address_space(1))) void*)g,
        (__attribute__((address_space(3))) void*)l, 16, 0, 0);
}

// ---- fused prep (UNCHANGED) ----
__global__ __launch_bounds__(256)
void prep(const float* __restrict__ aam, const float* __restrict__ gcw,
          const float* __restrict__ hmat,
          unsigned short* __restrict__ Abf, unsigned short* __restrict__ XT)
{
    const int tid = threadIdx.x;
    if ((int)blockIdx.x < MDIM) {
        const int i = blockIdx.x;
        __shared__ float sm[64];
        if (tid < 64) sm[tid] = aam[(size_t)(i & 63) * KDIM + tid];
        __syncthreads();
        const size_t base = (size_t)i * KDIM + tid * 16;
        floatx4 w0 = *(const floatx4*)(gcw + base);
        floatx4 w1 = *(const floatx4*)(gcw + base + 4);
        floatx4 w2 = *(const floatx4*)(gcw + base + 8);
        floatx4 w3 = *(const floatx4*)(gcw + base + 12);
        const float* m = &sm[(tid & 3) * 16];
        short8 p0, p1;
#pragma unroll
        for (int e = 0; e < 4; ++e) {
            float v0 = m[e]      * w0[e]; v0 = v0 > 0.f ? v0 : 0.f;
            float v1 = m[e + 4]  * w1[e]; v1 = v1 > 0.f ? v1 : 0.f;
            float v2 = m[e + 8]  * w2[e]; v2 = v2 > 0.f ? v2 : 0.f;
            float v3 = m[e + 12] * w3[e]; v3 = v3 > 0.f ? v3 : 0.f;
            p0[e]     = (short)f2bf(v0);
            p0[e + 4] = (short)f2bf(v1);
            p1[e]     = (short)f2bf(v2);
            p1[e + 4] = (short)f2bf(v3);
        }
        *(short8*)(Abf + base)     = p0;
        *(short8*)(Abf + base + 8) = p1;
    } else {
        const int blk = blockIdx.x - MDIM;
        const int b = blk >> 6;
        const int t = blk & 63;
        const int c0 = (tid & 7) * 8;
        const int d0 = tid >> 3;
#pragma unroll
        for (int it = 0; it < 4; ++it) {
            const int d = d0 + it * 32;
            short8 p;
#pragma unroll
            for (int e = 0; e < 8; ++e) {
                float v = hmat[(((size_t)b * NC + (c0 + e)) * NT + t) * DH + d];
                p[e] = (short)f2bf(v);
            }
            *(short8*)(XT + ((size_t)(b * DH + d)) * KDIM + t * 64 + c0) = p;
        }
    }
}

// ---- GEMM: C[4096, 2048] = A @ XT^T, triple-buffer + counted vmcnt + phases ----
__global__ __launch_bounds__(512, 2)
void gemm(const unsigned short* __restrict__ Abf,
          const unsigned short* __restrict__ XT,
          const float* __restrict__ gcb,
          float* __restrict__ out)
{
    __shared__ short lds[3][(BM + BN) * BK];   // 3 x 48 KB = 144 KB

    const int tid = threadIdx.x;
    const int bid = blockIdx.x;
    const int np  = bid & 7;        // n-panel 0..7 -> one per XCD (X panel L2-fits)
    const int mp  = bid >> 3;       // m-panel 0..31
    const int i0  = mp * BM;
    const int n0  = np * BN;

    const int lane = tid & 63;
    const int w    = tid >> 6;          // 0..7
    const int wm   = (w >> 2) * 64;     // 2 M-warps
    const int wn   = (w & 3) * 64;      // 4 N-warps
    const int l15  = lane & 15;
    const int q    = lane >> 4;

    const int srow = lane >> 3;         // 0..7: row within 8-row group
    const int swz  = ((lane & 7) ^ srow) << 3;   // swizzled k-chunk (elements)

    const unsigned short* Ab = Abf + (size_t)i0 * KDIM + swz;
    const unsigned short* Xb = XT  + (size_t)n0 * KDIM + swz;

    floatx4 acc[4][4];
#pragma unroll
    for (int mi = 0; mi < 4; ++mi)
#pragma unroll
        for (int ni = 0; ni < 4; ++ni)
            acc[mi][ni] = (floatx4){0.f, 0.f, 0.f, 0.f};

    // full-tile stage (prologue / generic): 6 global_load_lds, linear LDS dest,
    // swizzle carried on the per-lane GLOBAL source address
    auto stage = [&](int t, int b) {
        const int k0 = t * BK;
        short* dst = lds[b];
#pragma unroll
        for (int ii = 0; ii < 2; ++ii) {
            const int r = ii * 64 + w * 8 + srow;
            async16(Ab + (size_t)r * KDIM + k0, dst + (ii * 64 + w * 8) * BK);
        }
#pragma unroll
        for (int ii = 0; ii < 4; ++ii) {
            const int r = ii * 64 + w * 8 + srow;
            async16(Xb + (size_t)r * KDIM + k0, dst + (BM + ii * 64 + w * 8) * BK);
        }
    };

    // final-tile compute (no phases needed, runs once)
    auto compute = [&](int b) {
        const short* sA = lds[b];
        const short* sX = lds[b] + BM * BK;
#pragma unroll
        for (int h = 0; h < 2; ++h) {
            const int co = ((h * 4 + q) ^ (l15 & 7)) << 3;
            short8 af[4], xf[4];
#pragma unroll
            for (int mi = 0; mi < 4; ++mi)
                af[mi] = *(const short8*)&sA[(wm + mi * 16 + l15) * BK + co];
#pragma unroll
            for (int ni = 0; ni < 4; ++ni)
                xf[ni] = *(const short8*)&sX[(wn + ni * 16 + l15) * BK + co];
            __builtin_amdgcn_s_setprio(1);
#pragma unroll
            for (int mi = 0; mi < 4; ++mi)
#pragma unroll
                for (int ni = 0; ni < 4; ++ni)
                    acc[mi][ni] = __builtin_amdgcn_mfma_f32_16x16x32_bf16(
                        af[mi], xf[ni], acc[mi][ni], 0, 0, 0);
            __builtin_amdgcn_s_setprio(0);
        }
    };

    stage(0, 0);
    stage(1, 1);

    int bc = 0;   // buffer holding tile t
    for (int t = 0; t < NTILES - 1; ++t) {
        const short* sA = lds[bc];
        const short* sX = sA + BM * BK;
        int bs = bc + 2; if (bs >= 3) bs -= 3;
        short* dst = lds[bs];
        const int k2 = (t + 2) * BK;
        const bool st = (t + 2 < NTILES);

        // own tile-t loads retired; tile-(t+1)'s 6 stay in flight
        asm volatile("s_waitcnt vmcnt(6)" ::: "memory");
        __builtin_amdgcn_s_barrier();

        short8 af[4], xf[4];
        // ---- phase 0 (h=0): issue reads + 3 stage loads, bar, mfma, bar ----
        {
            const int co = (q ^ (l15 & 7)) << 3;
#pragma unroll
            for (int mi = 0; mi < 4; ++mi)
                af[mi] = *(const short8*)&sA[(wm + mi * 16 + l15) * BK + co];
#pragma unroll
            for (int ni = 0; ni < 4; ++ni)
                xf[ni] = *(const short8*)&sX[(wn + ni * 16 + l15) * BK + co];
        }
        if (st) {
            async16(Ab + (size_t)(w * 8 + srow) * KDIM + k2,        dst + (w * 8) * BK);
            async16(Ab + (size_t)(64 + w * 8 + srow) * KDIM + k2,   dst + (64 + w * 8) * BK);
            async16(Xb + (size_t)(w * 8 + srow) * KDIM + k2,        dst + (BM + w * 8) * BK);
        }
        __builtin_amdgcn_s_barrier();
        __builtin_amdgcn_s_setprio(1);
#pragma unroll
        for (int mi = 0; mi < 4; ++mi)
#pragma unroll
            for (int ni = 0; ni < 4; ++ni)
                acc[mi][ni] = __builtin_amdgcn_mfma_f32_16x16x32_bf16(
                    af[mi], xf[ni], acc[mi][ni], 0, 0, 0);
        __builtin_amdgcn_s_setprio(0);
        __builtin_amdgcn_s_barrier();

        // ---- phase 1 (h=1): issue reads + remaining 3 stage loads, bar, mfma ----
        {
            const int co = ((4 + q) ^ (l15 & 7)) << 3;
#pragma unroll
            for (int mi = 0; mi < 4; ++mi)
                af[mi] = *(const short8*)&sA[(wm + mi * 16 + l15) * BK + co];
#pragma unroll
            for (int ni = 0; ni < 4; ++ni)
                xf[ni] = *(const short8*)&sX[(wn + ni * 16 + l15) * BK + co];
        }
        if (st) {
            async16(Xb + (size_t)(64 + w * 8 + srow) * KDIM + k2,   dst + (BM + 64 + w * 8) * BK);
            async16(Xb + (size_t)(128 + w * 8 + srow) * KDIM + k2,  dst + (BM + 128 + w * 8) * BK);
            async16(Xb + (size_t)(192 + w * 8 + srow) * KDIM + k2,  dst + (BM + 192 + w * 8) * BK);
        }
        __builtin_amdgcn_s_barrier();
        __builtin_amdgcn_s_setprio(1);
#pragma unroll
        for (int mi = 0; mi < 4; ++mi)
#pragma unroll
            for (int ni = 0; ni < 4; ++ni)
                acc[mi][ni] = __builtin_amdgcn_mfma_f32_16x16x32_bf16(
                    af[mi], xf[ni], acc[mi][ni], 0, 0, 0);
        __builtin_amdgcn_s_setprio(0);
        // tile-end alignment = next iteration's top barrier

        if (++bc == 3) bc = 0;
    }
    asm volatile("s_waitcnt vmcnt(0)" ::: "memory");
    __builtin_amdgcn_s_barrier();
    asm volatile("" ::: "memory");
    compute(bc);

    // epilogue: + GCB (fp32), relu, permuted store out[b, s=i&63, t=i>>6, d]
#pragma unroll
    for (int mi = 0; mi < 4; ++mi) {
        const int ibase = i0 + wm + mi * 16 + q * 4;   // C/D: row = q*4 + reg
#pragma unroll
        for (int ni = 0; ni < 4; ++ni) {
            const int n  = n0 + wn + ni * 16 + l15;    // global col 0..2047
            const int bb = n >> 7;
            const int d  = n & 127;
#pragma unroll
            for (int r = 0; r < 4; ++r) {
                const int i = ibase + r;
                float v = acc[mi][ni][r] + gcb[(size_t)i * DH + d];
                v = v > 0.f ? v : 0.f;
                out[(((size_t)bb * NS + (i & 63)) * NT + (i >> 6)) * DH + d] = v;
            }
        }
    }
}

// ---- fallback: fused kernel (used only if ws too small) ----
#define APAD 40
#define XPAD 20
__global__ __launch_bounds__(256, 2)
void gcn_fused(const float* __restrict__ hmat, const float* __restrict__ aam,
               const float* __restrict__ gcw, const float* __restrict__ gcb,
               float* __restrict__ out)
{
    __shared__ short sA[TM * APAD];
    __shared__ unsigned int sX[DH * XPAD];
    const int tid = threadIdx.x;
    const int bid = blockIdx.x;
    const int mp  = (bid & 7) * 4 + (bid >> 7);
    const int b   = (bid >> 3) & 15;
    const int i0  = mp * TM;
    const int lane = tid & 63;
    const int wm = ((tid >> 6) >> 1) * 64;
    const int wn = ((tid >> 6) & 1) * 64;
    const int l15 = lane & 15;
    const int q   = lane >> 4;
    floatx4 acc[4][4];
#pragma unroll
    for (int mi = 0; mi < 4; ++mi)
#pragma unroll
        for (int ni = 0; ni < 4; ++ni) acc[mi][ni] = (floatx4){0.f,0.f,0.f,0.f};
    const int ar = tid >> 2, ac = (tid & 3) << 3;
    const int kp = tid >> 4, dg = (tid & 15) << 3;
    const int wkey = (tid & 3) << 2;
    for (int k0 = 0; k0 < KDIM; k0 += 32) {
        const size_t ga0 = (size_t)(i0 + ar) * KDIM + (k0 + ac);
        const size_t ga1 = ga0 + (size_t)64 * KDIM;
        floatx4 aa0a = *(const floatx4*)(aam + ga0), aa0b = *(const floatx4*)(aam + ga0 + 4);
        floatx4 ww0a = *(const floatx4*)(gcw + ga0), ww0b = *(const floatx4*)(gcw + ga0 + 4);
        floatx4 aa1a = *(const floatx4*)(aam + ga1), aa1b = *(const floatx4*)(aam + ga1 + 4);
        floatx4 ww1a = *(const floatx4*)(gcw + ga1), ww1b = *(const floatx4*)(gcw + ga1 + 4);
        const int jj = k0 + 2 * kp, tt = jj >> 6, cc = jj & 63;
        const size_t gx0 = ((size_t)(b * NC + cc) * NT + tt) * DH + dg;
        const size_t gx1 = gx0 + (size_t)NT * DH;
        floatx4 x0a = *(const floatx4*)(hmat + gx0), x0b = *(const floatx4*)(hmat + gx0 + 4);
        floatx4 x1a = *(const floatx4*)(hmat + gx1), x1b = *(const floatx4*)(hmat + gx1 + 4);
        __syncthreads();
        short8 p0, p1;
#pragma unroll
        for (int e = 0; e < 4; ++e) {
            float v0 = aa0a[e]*ww0a[e]; v0 = v0>0.f?v0:0.f;
            float v1 = aa0b[e]*ww0b[e]; v1 = v1>0.f?v1:0.f;
            float v2 = aa1a[e]*ww1a[e]; v2 = v2>0.f?v2:0.f;
            float v3 = aa1b[e]*ww1b[e]; v3 = v3>0.f?v3:0.f;
            p0[e] = (short)f2bf(v0); p0[e+4] = (short)f2bf(v1);
            p1[e] = (short)f2bf(v2); p1[e+4] = (short)f2bf(v3);
        }
        *(short8*)&sA[ar * APAD + ac] = p0;
        *(short8*)&sA[(ar + 64) * APAD + ac] = p1;
#pragma unroll
        for (int e = 0; e < 4; ++e) {
            unsigned int pka = (unsigned int)f2bf(x0a[e]) | ((unsigned int)f2bf(x1a[e]) << 16);
            unsigned int pkb = (unsigned int)f2bf(x0b[e]) | ((unsigned int)f2bf(x1b[e]) << 16);
            sX[(dg + e) * XPAD + (kp ^ wkey)] = pka;
            sX[(dg + e + 4) * XPAD + (kp ^ wkey)] = pkb;
        }
        __syncthreads();
        short8 afrag[4], bfrag[4];
#pragma unroll
        for (int mi = 0; mi < 4; ++mi)
            afrag[mi] = *(const short8*)&sA[(wm + mi * 16 + l15) * APAD + q * 8];
#pragma unroll
        for (int ni = 0; ni < 4; ++ni) {
            const int row = wn + ni * 16 + l15;
            const int col = (q * 4) ^ (((row >> 3) & 3) << 2);
            bfrag[ni] = *(const short8*)(sX + row * XPAD + col);
        }
#pragma unroll
        for (int mi = 0; mi < 4; ++mi)
#pragma unroll
            for (int ni = 0; ni < 4; ++ni)
                acc[mi][ni] = __builtin_amdgcn_mfma_f32_16x16x32_bf16(
                    afrag[mi], bfrag[ni], acc[mi][ni], 0, 0, 0);
    }
#pragma unroll
    for (int mi = 0; mi < 4; ++mi) {
        const int ibase = i0 + wm + mi * 16 + q * 4;
#pragma unroll
        for (int ni = 0; ni < 4; ++ni) {
            const int d = wn + ni * 16 + l15;
#pragma unroll
            for (int r = 0; r < 4; ++r) {
                const int i = ibase + r;
                float v = acc[mi][ni][r] + gcb[(size_t)i * DH + d];
                v = v > 0.f ? v : 0.f;
                out[(((size_t)b * NS + (i & 63)) * NT + (i >> 6)) * DH + d] = v;
            }
        }
    }
}

extern "C" void kernel_launch(void* const* d_in, const int* in_sizes, int n_in,
                              void* d_out, int out_size, void* d_ws, size_t ws_size,
                              hipStream_t stream) {
    const float* h   = (const float*)d_in[0];
    const float* aam = (const float*)d_in[2];
    const float* gcw = (const float*)d_in[3];
    const float* gcb = (const float*)d_in[4];
    float* out = (float*)d_out;

    const size_t A_BYTES  = (size_t)MDIM * KDIM * 2;            // 33.55 MB
    const size_t XT_BYTES = (size_t)BATCH * DH * KDIM * 2;      // 16.78 MB

    if (ws_size >= A_BYTES + XT_BYTES) {
        unsigned short* Abf = (unsigned short*)d_ws;
        unsigned short* XT  = (unsigned short*)((char*)d_ws + A_BYTES);
        prep<<<dim3(MDIM + BATCH * NT), 256, 0, stream>>>(aam, gcw, h, Abf, XT);
        gemm<<<dim3((MDIM / BM) * (BATCH * DH / BN)), 512, 0, stream>>>(Abf, XT, gcb, out);
    } else {
        gcn_fused<<<dim3((MDIM / TM) * BATCH), 256, 0, stream>>>(h, aam, gcw, gcb, out);
    }
}

// Round 4
// 229.297 us; speedup vs baseline: 1.0410x; 1.0410x over previous
//
#include <hip/hip_runtime.h>

// GCNFast: out[b,s,t,d] = relu( sum_j relu(AA[i%64,j%64]*GCW[i,j]) * X[j,b,d] + GCB[i,d] )
// SPARSITY RESTRUCTURE: AA (64x64, ~50% dense) gives every row-group s=i%64 a fixed
// support supp(s) in c=j%64. Reorder K as kk=c*64+t so zero columns become whole
// zero K-tiles -> skip them. A' compact (per-s rows, kk=ci*64+t), XT' reordered
// [n][c*64+t] (naturally coalesced from h). gemm: per-s 64x256 tiles, 4 waves,
// 2 blocks/CU (LDS 2x40KB dbuf = exactly 160KB/CU), round-2 counted-vmcnt loop
// (round-3's per-phase barriers regressed -> reverted). K-loop runs ns[s]~32 of 64 tiles.
// Fallback to fused single-kernel path if ws too small.

#define NC 64
#define NS 64
#define NT 64
#define DH 128
#define BATCH 16
#define MDIM 4096
#define KDIM 4096
#define KPAD 4096
#define TM 128
#define TK 64
#define GBM 64
#define GBN 256
#define GBK 64

typedef __attribute__((ext_vector_type(8))) short short8;
typedef __attribute__((ext_vector_type(4))) short short4v;
typedef __attribute__((ext_vector_type(4))) float floatx4;

__device__ __forceinline__ unsigned short f2bf(float f) {
    union { float f; unsigned int i; } v; v.f = f;
    return (unsigned short)((v.i + 0x7fffu + ((v.i >> 16) & 1u)) >> 16);
}
__device__ __forceinline__ void async16(const void* g, void* l) {
    __builtin_amdgcn_global_load_lds(
        (const __attribute__((address_space(1))) void*)g,
        (__attribute__((address_space(3))) void*)l, 16, 0, 0);
}

// ---- fused prep ----
// blocks [0,4096): A'-compact row r=s*64+tt (original row i=tt*64+s):
//   A'[r][ci*64+t] = relu(GCW[i][t*64+cidx[s][ci]]) as bf16 (AA=1 on support).
//   GCW read coalesced -> LDS full row -> gathered compact write (coalesced).
//   Blocks with tt==0 also publish cidx[s][.], ns[s] to ws.
// blocks [4096,5120): XT'[b*128+d][c*64+t] = bf16(h[b,c,t,d]) via LDS transpose;
//   both global sides fully coalesced.
__global__ __launch_bounds__(256)
void prep(const float* __restrict__ aam, const float* __restrict__ gcw,
          const float* __restrict__ hmat,
          unsigned short* __restrict__ Abf, unsigned short* __restrict__ XT,
          unsigned short* __restrict__ cidx, int* __restrict__ nsb)
{
    const int tid = threadIdx.x;
    if ((int)blockIdx.x < MDIM) {
        const int r  = blockIdx.x;
        const int s  = r >> 6;
        const int tt = r & 63;
        const int i  = tt * 64 + s;
        __shared__ unsigned short scidx[64];
        __shared__ int sns;
        __shared__ unsigned short srow[4096];
        if (tid < 64) {
            float v = aam[(size_t)s * KDIM + tid];
            unsigned long long m = __ballot(v != 0.f);
            int rank = __popcll(m & ((1ull << tid) - 1ull));
            if (v != 0.f) scidx[rank] = (unsigned short)tid;
            if (tid == 0) sns = (int)__popcll(m);
            if (tt == 0) {
                if (v != 0.f) cidx[s * 64 + rank] = (unsigned short)tid;
                if (tid == 0) nsb[s] = (int)__popcll(m);
            }
        }
        const float* gr = gcw + (size_t)i * KDIM;
#pragma unroll
        for (int u = 0; u < 4; ++u) {
            const int idx = u * 1024 + tid * 4;
            floatx4 wv = *(const floatx4*)(gr + idx);
            short4v p;
#pragma unroll
            for (int e = 0; e < 4; ++e) {
                float v = wv[e] > 0.f ? wv[e] : 0.f;
                p[e] = (short)f2bf(v);
            }
            *(short4v*)&srow[idx] = p;
        }
        __syncthreads();
        const int ke = sns * 64;   // multiple of 64
        for (int kk0 = tid * 8; kk0 < ke; kk0 += 2048) {
            const int c  = (int)scidx[kk0 >> 6];
            const int t0 = kk0 & 63;   // multiple of 8, t0+7 <= 63
            short8 p;
#pragma unroll
            for (int e = 0; e < 8; ++e)
                p[e] = (short)srow[(t0 + e) * 64 + c];
            *(short8*)(Abf + (size_t)r * KPAD + kk0) = p;
        }
    } else {
        const int blk = blockIdx.x - MDIM;
        const int b = blk >> 6;
        const int c = blk & 63;
        __shared__ unsigned short sx[64][136];   // pad: stride 272B (16B-aligned, bank-spread)
        const float* hp = hmat + (((size_t)b * NC + c) * NT) * DH;
#pragma unroll
        for (int u = 0; u < 8; ++u) {
            const int idx = u * 1024 + tid * 4;   // float idx in [64t][128d]
            const int t = idx >> 7;
            const int d = idx & 127;
            floatx4 v = *(const floatx4*)(hp + idx);
            short4v p;
#pragma unroll
            for (int e = 0; e < 4; ++e) p[e] = (short)f2bf(v[e]);
            *(short4v*)&sx[t][d] = p;
        }
        __syncthreads();
        const int d  = tid >> 1;
        const int th = (tid & 1) * 32;
        unsigned short* dst = XT + ((size_t)(b * DH + d)) * KPAD + c * 64 + th;
#pragma unroll
        for (int u2 = 0; u2 < 4; ++u2) {
            short8 p;
#pragma unroll
            for (int e = 0; e < 8; ++e)
                p[e] = (short)sx[th + u2 * 8 + e][d];
            *(short8*)(dst + u2 * 8) = p;
        }
    }
}

// ---- GEMM: per-s tile C[64, 256], K over ns[s] nonzero c-tiles ----
__global__ __launch_bounds__(256, 2)
void gemm(const unsigned short* __restrict__ Abf,
          const unsigned short* __restrict__ XT,
          const unsigned short* __restrict__ cidx,
          const int* __restrict__ nsb,
          const float* __restrict__ gcb,
          float* __restrict__ out)
{
    __shared__ short lds[2][(GBM + GBN) * GBK];   // 2 x 40 KB = 80 KB (2 blocks/CU = 160KB)

    const int tid = threadIdx.x;
    const int bid = blockIdx.x;
    const int np = bid & 7;        // n-panel -> one per XCD (XT' panel 2MB L2-fits)
    const int s  = bid >> 3;       // row-group 0..63
    const int n0 = np * GBN;

    const int lane = tid & 63;
    const int w    = tid >> 6;     // 0..3
    const int wn   = w * 64;
    const int l15  = lane & 15;
    const int q    = lane >> 4;
    const int srow = lane >> 3;
    const int swz  = ((lane & 7) ^ srow) << 3;   // swizzled k-chunk (elements)

    const int nt = nsb[s];                        // K-tiles = |supp(s)|
    const int cl = (int)cidx[s * 64 + lane];      // lane t holds c(t) (t<nt valid)

    const unsigned short* Ab = Abf + (size_t)(s * 64) * KPAD + swz;
    const unsigned short* Xb = XT  + (size_t)n0 * KPAD + swz;

    floatx4 acc[4][4];
#pragma unroll
    for (int mi = 0; mi < 4; ++mi)
#pragma unroll
        for (int ni = 0; ni < 4; ++ni)
            acc[mi][ni] = (floatx4){0.f, 0.f, 0.f, 0.f};

    // 10 global_load_lds per wave per tile (2 A-groups + 8 X-groups)
    auto stage = [&](int t, int b) {
        short* dst = lds[b];
        const int c = __shfl(cl, t);
        const size_t ka = (size_t)t * GBK;   // A' compact k-offset
        const size_t kx = (size_t)c * GBK;   // XT' reordered k-offset
        async16(Ab + (size_t)(w * 8 + srow) * KPAD + ka,       dst + (w * 8) * GBK);
        async16(Ab + (size_t)((w + 4) * 8 + srow) * KPAD + ka, dst + ((w + 4) * 8) * GBK);
#pragma unroll
        for (int g = 0; g < 8; ++g) {
            const int rr = w * 64 + g * 8;
            async16(Xb + (size_t)(rr + srow) * KPAD + kx, dst + (GBM + rr) * GBK);
        }
    };

    auto compute = [&](int b) {
        const short* sA = lds[b];
        const short* sX = lds[b] + GBM * GBK;
#pragma unroll
        for (int h2 = 0; h2 < 2; ++h2) {
            const int co = ((h2 * 4 + q) ^ (l15 & 7)) << 3;
            short8 af[4], xf[4];
#pragma unroll
            for (int mi = 0; mi < 4; ++mi)
                af[mi] = *(const short8*)&sA[(mi * 16 + l15) * GBK + co];
#pragma unroll
            for (int ni = 0; ni < 4; ++ni)
                xf[ni] = *(const short8*)&sX[(wn + ni * 16 + l15) * GBK + co];
            __builtin_amdgcn_s_setprio(1);
#pragma unroll
            for (int mi = 0; mi < 4; ++mi)
#pragma unroll
                for (int ni = 0; ni < 4; ++ni)
                    acc[mi][ni] = __builtin_amdgcn_mfma_f32_16x16x32_bf16(
                        af[mi], xf[ni], acc[mi][ni], 0, 0, 0);
            __builtin_amdgcn_s_setprio(0);
        }
    };

    if (nt > 0) stage(0, 0);
    if (nt > 1) stage(1, 1);
    for (int t = 0; t < nt - 1; ++t) {
        // t's 10 loads retired; (t+1)'s 10 stay in flight
        asm volatile("s_waitcnt vmcnt(10)" ::: "memory");
        __builtin_amdgcn_s_barrier();
        compute(t & 1);
        __builtin_amdgcn_s_barrier();
        if (t + 2 < nt) stage(t + 2, t & 1);
    }
    if (nt > 0) {
        asm volatile("s_waitcnt vmcnt(0)" ::: "memory");
        __builtin_amdgcn_s_barrier();
        compute((nt - 1) & 1);
    }

    // epilogue: row-in-tile tt -> original i = tt*64 + s; out[b, s, tt, d]
#pragma unroll
    for (int mi = 0; mi < 4; ++mi) {
        const int tt0 = mi * 16 + q * 4;
#pragma unroll
        for (int ni = 0; ni < 4; ++ni) {
            const int n  = n0 + wn + ni * 16 + l15;
            const int bb = n >> 7;
            const int d  = n & 127;
#pragma unroll
            for (int r = 0; r < 4; ++r) {
                const int tt = tt0 + r;
                const int i  = tt * 64 + s;
                float v = acc[mi][ni][r] + gcb[(size_t)i * DH + d];
                v = v > 0.f ? v : 0.f;
                out[(((size_t)bb * NS + s) * NT + tt) * DH + d] = v;
            }
        }
    }
}

// ---- fallback: fused kernel (used only if ws too small) ----
#define APAD 40
#define XPAD 20
__global__ __launch_bounds__(256, 2)
void gcn_fused(const float* __restrict__ hmat, const float* __restrict__ aam,
               const float* __restrict__ gcw, const float* __restrict__ gcb,
               float* __restrict__ out)
{
    __shared__ short sA[TM * APAD];
    __shared__ unsigned int sX[DH * XPAD];
    const int tid = threadIdx.x;
    const int bid = blockIdx.x;
    const int mp  = (bid & 7) * 4 + (bid >> 7);
    const int b   = (bid >> 3) & 15;
    const int i0  = mp * TM;
    const int lane = tid & 63;
    const int wm = ((tid >> 6) >> 1) * 64;
    const int wn = ((tid >> 6) & 1) * 64;
    const int l15 = lane & 15;
    const int q   = lane >> 4;
    floatx4 acc[4][4];
#pragma unroll
    for (int mi = 0; mi < 4; ++mi)
#pragma unroll
        for (int ni = 0; ni < 4; ++ni) acc[mi][ni] = (floatx4){0.f,0.f,0.f,0.f};
    const int ar = tid >> 2, ac = (tid & 3) << 3;
    const int kp = tid >> 4, dg = (tid & 15) << 3;
    const int wkey = (tid & 3) << 2;
    for (int k0 = 0; k0 < KDIM; k0 += 32) {
        const size_t ga0 = (size_t)(i0 + ar) * KDIM + (k0 + ac);
        const size_t ga1 = ga0 + (size_t)64 * KDIM;
        floatx4 aa0a = *(const floatx4*)(aam + ga0), aa0b = *(const floatx4*)(aam + ga0 + 4);
        floatx4 ww0a = *(const floatx4*)(gcw + ga0), ww0b = *(const floatx4*)(gcw + ga0 + 4);
        floatx4 aa1a = *(const floatx4*)(aam + ga1), aa1b = *(const floatx4*)(aam + ga1 + 4);
        floatx4 ww1a = *(const floatx4*)(gcw + ga1), ww1b = *(const floatx4*)(gcw + ga1 + 4);
        const int jj = k0 + 2 * kp, tt = jj >> 6, cc = jj & 63;
        const size_t gx0 = ((size_t)(b * NC + cc) * NT + tt) * DH + dg;
        const size_t gx1 = gx0 + (size_t)NT * DH;
        floatx4 x0a = *(const floatx4*)(hmat + gx0), x0b = *(const floatx4*)(hmat + gx0 + 4);
        floatx4 x1a = *(const floatx4*)(hmat + gx1), x1b = *(const floatx4*)(hmat + gx1 + 4);
        __syncthreads();
        short8 p0, p1;
#pragma unroll
        for (int e = 0; e < 4; ++e) {
            float v0 = aa0a[e]*ww0a[e]; v0 = v0>0.f?v0:0.f;
            float v1 = aa0b[e]*ww0b[e]; v1 = v1>0.f?v1:0.f;
            float v2 = aa1a[e]*ww1a[e]; v2 = v2>0.f?v2:0.f;
            float v3 = aa1b[e]*ww1b[e]; v3 = v3>0.f?v3:0.f;
            p0[e] = (short)f2bf(v0); p0[e+4] = (short)f2bf(v1);
            p1[e] = (short)f2bf(v2); p1[e+4] = (short)f2bf(v3);
        }
        *(short8*)&sA[ar * APAD + ac] = p0;
        *(short8*)&sA[(ar + 64) * APAD + ac] = p1;
#pragma unroll
        for (int e = 0; e < 4; ++e) {
            unsigned int pka = (unsigned int)f2bf(x0a[e]) | ((unsigned int)f2bf(x1a[e]) << 16);
            unsigned int pkb = (unsigned int)f2bf(x0b[e]) | ((unsigned int)f2bf(x1b[e]) << 16);
            sX[(dg + e) * XPAD + (kp ^ wkey)] = pka;
            sX[(dg + e + 4) * XPAD + (kp ^ wkey)] = pkb;
        }
        __syncthreads();
        short8 afrag[4], bfrag[4];
#pragma unroll
        for (int mi = 0; mi < 4; ++mi)
            afrag[mi] = *(const short8*)&sA[(wm + mi * 16 + l15) * APAD + q * 8];
#pragma unroll
        for (int ni = 0; ni < 4; ++ni) {
            const int row = wn + ni * 16 + l15;
            const int col = (q * 4) ^ (((row >> 3) & 3) << 2);
            bfrag[ni] = *(const short8*)(sX + row * XPAD + col);
        }
#pragma unroll
        for (int mi = 0; mi < 4; ++mi)
#pragma unroll
            for (int ni = 0; ni < 4; ++ni)
                acc[mi][ni] = __builtin_amdgcn_mfma_f32_16x16x32_bf16(
                    afrag[mi], bfrag[ni], acc[mi][ni], 0, 0, 0);
    }
#pragma unroll
    for (int mi = 0; mi < 4; ++mi) {
        const int ibase = i0 + wm + mi * 16 + q * 4;
#pragma unroll
        for (int ni = 0; ni < 4; ++ni) {
            const int d = wn + ni * 16 + l15;
#pragma unroll
            for (int r = 0; r < 4; ++r) {
                const int i = ibase + r;
                float v = acc[mi][ni][r] + gcb[(size_t)i * DH + d];
                v = v > 0.f ? v : 0.f;
                out[(((size_t)b * NS + (i & 63)) * NT + (i >> 6)) * DH + d] = v;
            }
        }
    }
}

extern "C" void kernel_launch(void* const* d_in, const int* in_sizes, int n_in,
                              void* d_out, int out_size, void* d_ws, size_t ws_size,
                              hipStream_t stream) {
    const float* h   = (const float*)d_in[0];
    const float* aam = (const float*)d_in[2];
    const float* gcw = (const float*)d_in[3];
    const float* gcb = (const float*)d_in[4];
    float* out = (float*)d_out;

    const size_t A_BYTES   = (size_t)MDIM * KPAD * 2;            // 33.55 MB
    const size_t XT_BYTES  = (size_t)BATCH * DH * KPAD * 2;      // 16.78 MB
    const size_t IDX_BYTES = 64 * 64 * 2;                        // 8 KB
    const size_t NS_BYTES  = 64 * 4;

    if (ws_size >= A_BYTES + XT_BYTES + IDX_BYTES + NS_BYTES) {
        unsigned short* Abf = (unsigned short*)d_ws;
        unsigned short* XTp = (unsigned short*)((char*)d_ws + A_BYTES);
        unsigned short* cid = (unsigned short*)((char*)d_ws + A_BYTES + XT_BYTES);
        int* nsb            = (int*)((char*)d_ws + A_BYTES + XT_BYTES + IDX_BYTES);
        prep<<<dim3(MDIM + BATCH * NT), 256, 0, stream>>>(aam, gcw, h, Abf, XTp, cid, nsb);
        gemm<<<dim3(64 * 8), 256, 0, stream>>>(Abf, XTp, cid, nsb, gcb, out);
    } else {
        gcn_fused<<<dim3((MDIM / TM) * BATCH), 256, 0, stream>>>(h, aam, gcw, gcb, out);
    }
}